// Round 1
// baseline (265.275 us; speedup 1.0000x reference)
//
#include <hip/hip_runtime.h>
#include <hip/hip_bf16.h>
#include <math.h>

// Problem constants (from reference): N=10000, E=160000, DIN=DOUT=256
#define D 256
#define CH 256          // edge chunk per node for online softmax
#define NEG_SLOPE 0.2f
#define BN_EPS 1e-5f

// ---------------------------------------------------------------------------
// Edge-index dtype detection: reference declares int64, harness doc says int32.
// If data is int64 (little-endian, values < 2^31), every odd 32-bit word is 0.
// ---------------------------------------------------------------------------
__global__ void detect_kernel(const int* __restrict__ ei, int* __restrict__ flag,
                              int nwords) {
    __shared__ int ok;
    if (threadIdx.x == 0) ok = 1;
    __syncthreads();
    for (int w = threadIdx.x * 2 + 1; w < nwords; w += 512) {
        if (ei[w] != 0) atomicAnd(&ok, 0);
    }
    __syncthreads();
    if (threadIdx.x == 0) *flag = ok;   // 1 => int64 layout
}

__global__ void convert_kernel(const int* __restrict__ ei, const int* __restrict__ flag,
                               int* __restrict__ eic, int n) {
    int e = blockIdx.x * 256 + threadIdx.x;
    if (e >= n) return;
    int is64 = *flag;
    eic[e] = is64 ? ei[2 * e] : ei[e];
}

// ---------------------------------------------------------------------------
// GEMM: Y = X * W + b  (fp32, 64x64 tile, BK=32, 4x4 per thread)
// blockIdx.z = 0 -> (Wl, bl, xl); 1 -> (Wr, br, xr)
// ---------------------------------------------------------------------------
#define BM 64
#define BN 64
#define BK 32

__global__ __launch_bounds__(256) void gemm_bias_kernel(
    const float* __restrict__ X,
    const float* __restrict__ Wl, const float* __restrict__ bl,
    const float* __restrict__ Wr, const float* __restrict__ br,
    float* __restrict__ xl, float* __restrict__ xr, int M)
{
    const float* W; const float* bv; float* Y;
    if (blockIdx.z == 0) { W = Wl; bv = bl; Y = xl; }
    else                 { W = Wr; bv = br; Y = xr; }

    __shared__ float As[BK][BM + 1];   // [k][m]
    __shared__ float Bs[BK][BN + 4];   // [k][n], +4 pad keeps rows 16B-aligned

    const int tid = threadIdx.x;
    const int tx = tid & 15;
    const int ty = tid >> 4;
    const int row0 = blockIdx.x * BM;
    const int col0 = blockIdx.y * BN;

    float acc[4][4] = {};

    for (int k0 = 0; k0 < D; k0 += BK) {
        #pragma unroll
        for (int i = 0; i < 2; i++) {
            int idx = tid + i * 256;          // 0..511
            // A tile: 64 x 32
            int am = idx >> 3;                // 0..63
            int ak = (idx & 7) << 2;          // 0,4,...,28
            float4 a = make_float4(0.f, 0.f, 0.f, 0.f);
            int row = row0 + am;
            if (row < M) a = *(const float4*)(X + (size_t)row * D + k0 + ak);
            As[ak + 0][am] = a.x; As[ak + 1][am] = a.y;
            As[ak + 2][am] = a.z; As[ak + 3][am] = a.w;
            // B tile: 32 x 64
            int bk = idx >> 4;                // 0..31
            int bn = (idx & 15) << 2;         // 0..60
            float4 b = *(const float4*)(W + (size_t)(k0 + bk) * D + col0 + bn);
            *(float4*)&Bs[bk][bn] = b;
        }
        __syncthreads();

        #pragma unroll
        for (int kk = 0; kk < BK; kk++) {
            float a[4], b[4];
            #pragma unroll
            for (int r = 0; r < 4; r++) a[r] = As[kk][ty * 4 + r];
            #pragma unroll
            for (int c = 0; c < 4; c++) b[c] = Bs[kk][tx * 4 + c];
            #pragma unroll
            for (int r = 0; r < 4; r++)
                #pragma unroll
                for (int c = 0; c < 4; c++)
                    acc[r][c] = fmaf(a[r], b[c], acc[r][c]);
        }
        __syncthreads();
    }

    float4 bias4 = *(const float4*)(bv + col0 + tx * 4);
    #pragma unroll
    for (int r = 0; r < 4; r++) {
        int row = row0 + ty * 4 + r;
        if (row < M) {
            float4 o;
            o.x = acc[r][0] + bias4.x;
            o.y = acc[r][1] + bias4.y;
            o.z = acc[r][2] + bias4.z;
            o.w = acc[r][3] + bias4.w;
            *(float4*)(Y + (size_t)row * D + col0 + tx * 4) = o;
        }
    }
}

// ---------------------------------------------------------------------------
// Counting sort of (E real + N self-loop) edges by destination
// ---------------------------------------------------------------------------
__global__ void hist_kernel(const int* __restrict__ eic, int* __restrict__ counts,
                            int E, int N) {
    int e = blockIdx.x * 256 + threadIdx.x;
    int M = E + N;
    if (e >= M) return;
    int dst = (e < E) ? eic[E + e] : (e - E);
    atomicAdd(&counts[dst], 1);
}

__global__ void scan_kernel(const int* __restrict__ counts, int* __restrict__ rowstart,
                            int n) {
    __shared__ int buf[256];
    __shared__ int carry;
    int tid = threadIdx.x;
    if (tid == 0) carry = 0;
    __syncthreads();
    for (int base = 0; base < n; base += 256) {
        int v = (base + tid < n) ? counts[base + tid] : 0;
        buf[tid] = v;
        __syncthreads();
        for (int off = 1; off < 256; off <<= 1) {
            int t = (tid >= off) ? buf[tid - off] : 0;
            __syncthreads();
            buf[tid] += t;
            __syncthreads();
        }
        int incl = buf[tid];
        int c = carry;
        if (base + tid < n) rowstart[base + tid] = c + incl - v;   // exclusive
        __syncthreads();
        if (tid == 255) carry = c + buf[255];
        __syncthreads();
    }
    if (tid == 0) rowstart[n] = carry;
}

__global__ void scatter_kernel(const int* __restrict__ eic,
                               const int* __restrict__ rowstart,
                               int* __restrict__ cursor, int* __restrict__ ssrc,
                               int E, int N) {
    int e = blockIdx.x * 256 + threadIdx.x;
    int M = E + N;
    if (e >= M) return;
    int src, dst;
    if (e < E) { src = eic[e]; dst = eic[E + e]; }
    else       { src = dst = e - E; }
    int pos = rowstart[dst] + atomicAdd(&cursor[dst], 1);
    ssrc[pos] = src;
}

// ---------------------------------------------------------------------------
// Per-destination-node: attention scores, online softmax, weighted aggregate,
// + bias + ReLU + dropout. Writes pre-BN activation to `out`.
// One block (256 threads = 4 waves) per node; thread t owns feature dim t.
// ---------------------------------------------------------------------------
__global__ __launch_bounds__(256) void node_kernel(
    const float* __restrict__ xl, const float* __restrict__ xr,
    const float* __restrict__ att, const float* __restrict__ bias,
    const float* __restrict__ du, const int* __restrict__ rowstart,
    const int* __restrict__ ssrc, float* __restrict__ out, int N)
{
    const int i = blockIdx.x;
    const int tid = threadIdx.x;
    const int lane = tid & 63;
    const int wave = tid >> 6;

    __shared__ __align__(16) float sxr[D];
    __shared__ float salpha[CH];
    __shared__ int   s_src[CH];
    __shared__ float red[4];

    sxr[tid] = xr[(size_t)i * D + tid];
    const float4 att4 = ((const float4*)att)[lane];
    __syncthreads();
    const float4 b4 = ((const float4*)sxr)[lane];

    const int start = rowstart[i];
    const int end   = rowstart[i + 1];

    float m = -INFINITY, l = 0.f, acc = 0.f;

    for (int c0 = start; c0 < end; c0 += CH) {
        int cn = min(CH, end - c0);

        // Phase A: one wave per edge computes att . leaky_relu(xl[src]+xr[i])
        for (int k = wave; k < cn; k += 4) {
            int src = ssrc[c0 + k];
            float4 a = ((const float4*)(xl + (size_t)src * D))[lane];
            float hx = a.x + b4.x; hx = hx > 0.f ? hx : NEG_SLOPE * hx;
            float hy = a.y + b4.y; hy = hy > 0.f ? hy : NEG_SLOPE * hy;
            float hz = a.z + b4.z; hz = hz > 0.f ? hz : NEG_SLOPE * hz;
            float hw = a.w + b4.w; hw = hw > 0.f ? hw : NEG_SLOPE * hw;
            float s = hx * att4.x + hy * att4.y + hz * att4.z + hw * att4.w;
            #pragma unroll
            for (int off = 32; off > 0; off >>= 1) s += __shfl_down(s, off);
            if (lane == 0) { salpha[k] = s; s_src[k] = src; }
        }
        __syncthreads();

        // chunk max
        float cm = -INFINITY;
        for (int k = tid; k < cn; k += 256) cm = fmaxf(cm, salpha[k]);
        #pragma unroll
        for (int off = 32; off > 0; off >>= 1) cm = fmaxf(cm, __shfl_down(cm, off));
        if (lane == 0) red[wave] = cm;
        __syncthreads();
        float mc = fmaxf(fmaxf(red[0], red[1]), fmaxf(red[2], red[3]));
        float mnew = fmaxf(m, mc);
        float scale = expf(m - mnew);      // expf(-inf)=0 on first chunk
        l *= scale; acc *= scale;
        __syncthreads();                   // red reads done before reuse

        // exponentiate + chunk sum
        float cs = 0.f;
        for (int k = tid; k < cn; k += 256) {
            float p = expf(salpha[k] - mnew);
            salpha[k] = p;
            cs += p;
        }
        #pragma unroll
        for (int off = 32; off > 0; off >>= 1) cs += __shfl_down(cs, off);
        if (lane == 0) red[wave] = cs;
        __syncthreads();
        l += red[0] + red[1] + red[2] + red[3];
        m = mnew;

        // weighted aggregation: thread t accumulates dim t over chunk edges
        for (int k = 0; k < cn; k++) {
            acc = fmaf(salpha[k], xl[(size_t)s_src[k] * D + tid], acc);
        }
        __syncthreads();                   // salpha/s_src reused next chunk
    }

    float v = acc / l + bias[tid];
    v = fmaxf(v, 0.f);
    float u = du[(size_t)i * D + tid];
    v = (u >= 0.5f) ? 2.f * v : 0.f;
    out[(size_t)i * D + tid] = v;
}

// ---------------------------------------------------------------------------
// BatchNorm (training stats): column sums/sumsq then normalize in-place
// ---------------------------------------------------------------------------
__global__ void bn_reduce_kernel(const float* __restrict__ pre,
                                 float* __restrict__ colsum,
                                 float* __restrict__ colsumsq, int N) {
    int t = threadIdx.x;
    float s = 0.f, s2 = 0.f;
    for (int r = blockIdx.x; r < N; r += gridDim.x) {
        float v = pre[(size_t)r * D + t];
        s += v; s2 += v * v;
    }
    atomicAdd(&colsum[t], s);
    atomicAdd(&colsumsq[t], s2);
}

__global__ void bn_apply_kernel(float* __restrict__ out,
                                const float* __restrict__ colsum,
                                const float* __restrict__ colsumsq,
                                const float* __restrict__ gamma,
                                const float* __restrict__ beta, int N) {
    int idx = blockIdx.x * 256 + threadIdx.x;
    int t = idx & (D - 1);
    float invN = 1.f / (float)N;
    float mean = colsum[t] * invN;
    float var = colsumsq[t] * invN - mean * mean;
    float inv = rsqrtf(var + BN_EPS);
    float v = out[idx];
    out[idx] = gamma[t] * (v - mean) * inv + beta[t];
}

// ---------------------------------------------------------------------------
extern "C" void kernel_launch(void* const* d_in, const int* in_sizes, int n_in,
                              void* d_out, int out_size, void* d_ws, size_t ws_size,
                              hipStream_t stream) {
    const float* x     = (const float*)d_in[0];
    const int*   ei    = (const int*)d_in[1];
    const float* Wl    = (const float*)d_in[2];
    const float* bl    = (const float*)d_in[3];
    const float* Wr    = (const float*)d_in[4];
    const float* br    = (const float*)d_in[5];
    const float* att   = (const float*)d_in[6];
    const float* bias  = (const float*)d_in[7];
    const float* gamma = (const float*)d_in[8];
    const float* beta  = (const float*)d_in[9];
    const float* du    = (const float*)d_in[10];

    const int N = in_sizes[0] / D;       // 10000
    const int E = in_sizes[1] / 2;       // 160000
    const int M = E + N;

    // workspace layout
    float* xl       = (float*)d_ws;
    float* xr       = xl + (size_t)N * D;
    float* colsum   = xr + (size_t)N * D;
    float* colsumsq = colsum + D;
    int*   counts   = (int*)(colsumsq + D);
    int*   rowstart = counts + N;
    int*   cursor   = rowstart + N + 1;
    int*   ssrc     = cursor + N;
    int*   eic      = ssrc + M;
    int*   flag     = eic + 2 * E;

    // zero: colsum, colsumsq, counts, rowstart, cursor (contiguous)
    size_t zero_bytes = (size_t)(2 * D + N + (N + 1) + N) * sizeof(int);
    hipMemsetAsync(colsum, 0, zero_bytes, stream);

    detect_kernel<<<1, 256, 0, stream>>>(ei, flag, 1024);
    convert_kernel<<<(2 * E + 255) / 256, 256, 0, stream>>>(ei, flag, eic, 2 * E);

    dim3 ggrid((N + BM - 1) / BM, D / BN, 2);
    gemm_bias_kernel<<<ggrid, 256, 0, stream>>>(x, Wl, bl, Wr, br, xl, xr, N);

    hist_kernel<<<(M + 255) / 256, 256, 0, stream>>>(eic, counts, E, N);
    scan_kernel<<<1, 256, 0, stream>>>(counts, rowstart, N);
    scatter_kernel<<<(M + 255) / 256, 256, 0, stream>>>(eic, rowstart, cursor, ssrc, E, N);

    node_kernel<<<N, 256, 0, stream>>>(xl, xr, att, bias, du, rowstart, ssrc,
                                       (float*)d_out, N);

    bn_reduce_kernel<<<256, 256, 0, stream>>>((const float*)d_out, colsum, colsumsq, N);
    bn_apply_kernel<<<N, 256, 0, stream>>>((float*)d_out, colsum, colsumsq,
                                           gamma, beta, N);
}

// Round 2
// 211.055 us; speedup vs baseline: 1.2569x; 1.2569x over previous
//
#include <hip/hip_runtime.h>
#include <hip/hip_bf16.h>
#include <math.h>

// N=10000, E=160000, DIN=DOUT=256
#define D 256
#define NEG_SLOPE 0.2f
#define BN_EPS 1e-5f

typedef __attribute__((ext_vector_type(8))) short bf16x8;
typedef __attribute__((ext_vector_type(8))) unsigned short ushort8;
typedef __attribute__((ext_vector_type(4))) float f32x4;

__device__ inline unsigned short f2bf(float f) {
    union { float f; unsigned u; } v; v.f = f;
    unsigned u = v.u;
    unsigned r = u + 0x7FFFu + ((u >> 16) & 1u);   // RNE
    return (unsigned short)(r >> 16);
}

// ---------------------------------------------------------------------------
// edge_index dtype detection (int64 little-endian => all odd words zero)
// ---------------------------------------------------------------------------
__global__ void detect_kernel(const int* __restrict__ ei, int* __restrict__ flag,
                              int nwords) {
    __shared__ int ok;
    if (threadIdx.x == 0) ok = 1;
    __syncthreads();
    for (int w = threadIdx.x * 2 + 1; w < nwords; w += 512) {
        if (ei[w] != 0) atomicAnd(&ok, 0);
    }
    __syncthreads();
    if (threadIdx.x == 0) *flag = ok;   // 1 => int64 layout
}

__global__ void convert_kernel(const int* __restrict__ ei, const int* __restrict__ flag,
                               int* __restrict__ eic, int n) {
    int e = blockIdx.x * 256 + threadIdx.x;
    if (e >= n) return;
    int is64 = *flag;
    eic[e] = is64 ? ei[2 * e] : ei[e];
}

// ---------------------------------------------------------------------------
// prep: Btcat[n][k] = (n<256 ? Wl : Wr)[k][n-...] as bf16, biascat[n]
// ---------------------------------------------------------------------------
__global__ void prep_kernel(const float* __restrict__ Wl, const float* __restrict__ bl,
                            const float* __restrict__ Wr, const float* __restrict__ br,
                            unsigned short* __restrict__ Bt, float* __restrict__ biascat) {
    int n = blockIdx.x;          // 0..511
    int k = threadIdx.x;         // 0..255
    const float* W = (n < 256) ? Wl : Wr;
    int nn = n & 255;
    Bt[(size_t)n * 256 + k] = f2bf(W[(size_t)k * 256 + nn]);
    if (k == 0) biascat[n] = (n < 256) ? bl[nn] : br[nn];
}

// ---------------------------------------------------------------------------
// MFMA GEMM: Y[10000][512] = X * [Wl|Wr] + biascat, split into xl / xr fp32.
// block 256 (4 waves), tile 64x64, BK=128 (2 stages of K=256).
// A staged fp32->bf16 on the fly; B pre-transposed bf16 (Bt[n][k]).
// ---------------------------------------------------------------------------
__global__ __launch_bounds__(256) void mfma_gemm_kernel(
    const float* __restrict__ X, const unsigned short* __restrict__ Bt,
    const float* __restrict__ biascat,
    float* __restrict__ xl, float* __restrict__ xr, int M)
{
    // pad 8 ushorts => row stride 272 B (16B-aligned, 2-way LDS conflict = free)
    __shared__ __align__(16) unsigned short As[64][136];
    __shared__ __align__(16) unsigned short Bs[64][136];

    const int tid = threadIdx.x;
    const int wave = tid >> 6, lane = tid & 63;
    const int m_l = lane & 15, quad = lane >> 4;
    const int row0 = blockIdx.x * 64;
    const int n0 = blockIdx.y * 64;

    f32x4 acc[4] = {};

    for (int k0 = 0; k0 < 256; k0 += 128) {
        __syncthreads();
        #pragma unroll
        for (int i = 0; i < 4; i++) {
            int c = tid + i * 256;          // 0..1023
            int r = c >> 4;                 // 0..63
            int kk = (c & 15) * 8;          // 0..120
            int grow = row0 + r;
            float4 f0, f1;
            if (grow < M) {
                f0 = *(const float4*)(X + (size_t)grow * 256 + k0 + kk);
                f1 = *(const float4*)(X + (size_t)grow * 256 + k0 + kk + 4);
            } else {
                f0 = make_float4(0.f, 0.f, 0.f, 0.f);
                f1 = f0;
            }
            ushort8 av;
            av[0] = f2bf(f0.x); av[1] = f2bf(f0.y); av[2] = f2bf(f0.z); av[3] = f2bf(f0.w);
            av[4] = f2bf(f1.x); av[5] = f2bf(f1.y); av[6] = f2bf(f1.z); av[7] = f2bf(f1.w);
            *(ushort8*)&As[r][kk] = av;
            *(ushort8*)&Bs[r][kk] = *(const ushort8*)(Bt + (size_t)(n0 + r) * 256 + k0 + kk);
        }
        __syncthreads();

        #pragma unroll
        for (int kk0 = 0; kk0 < 128; kk0 += 32) {
            bf16x8 a = *(const bf16x8*)&As[wave * 16 + m_l][kk0 + quad * 8];
            #pragma unroll
            for (int c = 0; c < 4; c++) {
                bf16x8 b = *(const bf16x8*)&Bs[c * 16 + m_l][kk0 + quad * 8];
                acc[c] = __builtin_amdgcn_mfma_f32_16x16x32_bf16(a, b, acc[c], 0, 0, 0);
            }
        }
    }

    #pragma unroll
    for (int c = 0; c < 4; c++) {
        int col = n0 + c * 16 + m_l;
        float bv = biascat[col];
        float* Y = (col < 256) ? xl : xr;
        int cc = col & 255;
        #pragma unroll
        for (int r = 0; r < 4; r++) {
            int row = row0 + wave * 16 + quad * 4 + r;
            if (row < M) Y[(size_t)row * 256 + cc] = acc[c][r] + bv;
        }
    }
}

// ---------------------------------------------------------------------------
// counting sort of (E real + N self-loop) edges by destination
// ---------------------------------------------------------------------------
__global__ void hist_kernel(const int* __restrict__ eic, int* __restrict__ counts,
                            int E, int N) {
    int e = blockIdx.x * 256 + threadIdx.x;
    int M = E + N;
    if (e >= M) return;
    int dst = (e < E) ? eic[E + e] : (e - E);
    atomicAdd(&counts[dst], 1);
}

// 1024-thread single-block scan: shfl wave scans, ~3 barriers per 1024 chunk
__global__ __launch_bounds__(1024) void scan_kernel(const int* __restrict__ counts,
                                                    int* __restrict__ rowstart, int n) {
    __shared__ int wsum[16];
    __shared__ int carry_s;
    int tid = threadIdx.x, lane = tid & 63, wid = tid >> 6;
    if (tid == 0) carry_s = 0;
    __syncthreads();
    for (int base = 0; base < n; base += 1024) {
        int idx = base + tid;
        int v = (idx < n) ? counts[idx] : 0;
        int x = v;
        #pragma unroll
        for (int off = 1; off < 64; off <<= 1) {
            int y = __shfl_up(x, off);
            if (lane >= off) x += y;
        }
        if (lane == 63) wsum[wid] = x;
        __syncthreads();                       // A
        int total = 0;
        if (wid == 0) {
            int w = (lane < 16) ? wsum[lane] : 0;
            #pragma unroll
            for (int off = 1; off < 16; off <<= 1) {
                int y = __shfl_up(w, off);
                if (lane >= off) w += y;
            }
            if (lane < 16) wsum[lane] = w;     // inclusive wave sums
            total = w;                          // lane 15 holds grand total
        }
        __syncthreads();                       // B
        int carry = carry_s;
        int woff = (wid > 0) ? wsum[wid - 1] : 0;
        if (idx < n) rowstart[idx] = carry + woff + x - v;   // exclusive
        __syncthreads();                       // C
        if (tid == 15) carry_s = carry + total;
        __syncthreads();
    }
    if (tid == 0) rowstart[n] = carry_s;
}

__global__ void scatter_kernel(const int* __restrict__ eic,
                               const int* __restrict__ rowstart,
                               int* __restrict__ cursor, int* __restrict__ ssrc,
                               int E, int N) {
    int e = blockIdx.x * 256 + threadIdx.x;
    int M = E + N;
    if (e >= M) return;
    int src, dst;
    if (e < E) { src = eic[e]; dst = eic[E + e]; }
    else       { src = dst = e - E; }
    int pos = rowstart[dst] + atomicAdd(&cursor[dst], 1);
    ssrc[pos] = src;
}

// ---------------------------------------------------------------------------
// One WAVE per node: single-pass flash-style attention + aggregate
// lane l owns dims 4l..4l+3 (float4). bias+ReLU+dropout fused; writes pre-BN.
// ---------------------------------------------------------------------------
__global__ __launch_bounds__(256) void node_kernel(
    const float* __restrict__ xl, const float* __restrict__ xr,
    const float* __restrict__ att, const float* __restrict__ bias,
    const float* __restrict__ du, const int* __restrict__ rowstart,
    const int* __restrict__ ssrc, float* __restrict__ out, int N)
{
    const int wave = threadIdx.x >> 6, lane = threadIdx.x & 63;
    const int i = blockIdx.x * 4 + wave;
    if (i >= N) return;

    const float4 att4 = ((const float4*)att)[lane];
    const float4 b4 = ((const float4*)(xr + (size_t)i * D))[lane];
    const int start = rowstart[i], end = rowstart[i + 1];

    float m = -INFINITY, lsum = 0.f;
    float4 acc = make_float4(0.f, 0.f, 0.f, 0.f);

    // 2-deep pipeline on the gathered row (deg >= 1 due to self-loops)
    int src0 = ssrc[start];
    float4 a = ((const float4*)(xl + (size_t)src0 * D))[lane];

    for (int e = start; e < end; e++) {
        float4 cur = a;
        if (e + 1 < end) {
            int s2 = ssrc[e + 1];
            a = ((const float4*)(xl + (size_t)s2 * D))[lane];
        }
        float hx = cur.x + b4.x; hx = (hx > 0.f) ? hx : NEG_SLOPE * hx;
        float hy = cur.y + b4.y; hy = (hy > 0.f) ? hy : NEG_SLOPE * hy;
        float hz = cur.z + b4.z; hz = (hz > 0.f) ? hz : NEG_SLOPE * hz;
        float hw = cur.w + b4.w; hw = (hw > 0.f) ? hw : NEG_SLOPE * hw;
        float s = hx * att4.x + hy * att4.y + hz * att4.z + hw * att4.w;
        #pragma unroll
        for (int off = 1; off < 64; off <<= 1) s += __shfl_xor(s, off);

        float mnew = fmaxf(m, s);
        float sc = __expf(m - mnew);      // 0 on first edge (m=-inf)
        float al = __expf(s - mnew);
        lsum = lsum * sc + al;
        acc.x = acc.x * sc + al * cur.x;
        acc.y = acc.y * sc + al * cur.y;
        acc.z = acc.z * sc + al * cur.z;
        acc.w = acc.w * sc + al * cur.w;
        m = mnew;
    }

    float inv = 1.f / lsum;
    float4 bi = ((const float4*)bias)[lane];
    float4 u4 = ((const float4*)(du + (size_t)i * D))[lane];
    float4 o;
    o.x = fmaxf(acc.x * inv + bi.x, 0.f); o.x = (u4.x >= 0.5f) ? 2.f * o.x : 0.f;
    o.y = fmaxf(acc.y * inv + bi.y, 0.f); o.y = (u4.y >= 0.5f) ? 2.f * o.y : 0.f;
    o.z = fmaxf(acc.z * inv + bi.z, 0.f); o.z = (u4.z >= 0.5f) ? 2.f * o.z : 0.f;
    o.w = fmaxf(acc.w * inv + bi.w, 0.f); o.w = (u4.w >= 0.5f) ? 2.f * o.w : 0.f;
    ((float4*)(out + (size_t)i * D))[lane] = o;
}

// ---------------------------------------------------------------------------
// BatchNorm (training stats)
// ---------------------------------------------------------------------------
__global__ void bn_reduce_kernel(const float* __restrict__ pre,
                                 float* __restrict__ colsum,
                                 float* __restrict__ colsumsq, int N) {
    int t = threadIdx.x;
    float s = 0.f, s2 = 0.f;
    for (int r = blockIdx.x; r < N; r += gridDim.x) {
        float v = pre[(size_t)r * D + t];
        s += v; s2 += v * v;
    }
    atomicAdd(&colsum[t], s);
    atomicAdd(&colsumsq[t], s2);
}

__global__ void bn_apply_kernel(float* __restrict__ out,
                                const float* __restrict__ colsum,
                                const float* __restrict__ colsumsq,
                                const float* __restrict__ gamma,
                                const float* __restrict__ beta, int N) {
    int idx4 = blockIdx.x * 256 + threadIdx.x;       // float4 index
    int t0 = (idx4 * 4) & (D - 1);
    float invN = 1.f / (float)N;
    float4 v = ((const float4*)out)[idx4];
    float4 o;
    {
        float mean = colsum[t0 + 0] * invN;
        float var = colsumsq[t0 + 0] * invN - mean * mean;
        o.x = gamma[t0 + 0] * (v.x - mean) * rsqrtf(var + BN_EPS) + beta[t0 + 0];
    }
    {
        float mean = colsum[t0 + 1] * invN;
        float var = colsumsq[t0 + 1] * invN - mean * mean;
        o.y = gamma[t0 + 1] * (v.y - mean) * rsqrtf(var + BN_EPS) + beta[t0 + 1];
    }
    {
        float mean = colsum[t0 + 2] * invN;
        float var = colsumsq[t0 + 2] * invN - mean * mean;
        o.z = gamma[t0 + 2] * (v.z - mean) * rsqrtf(var + BN_EPS) + beta[t0 + 2];
    }
    {
        float mean = colsum[t0 + 3] * invN;
        float var = colsumsq[t0 + 3] * invN - mean * mean;
        o.w = gamma[t0 + 3] * (v.w - mean) * rsqrtf(var + BN_EPS) + beta[t0 + 3];
    }
    ((float4*)out)[idx4] = o;
}

// ---------------------------------------------------------------------------
extern "C" void kernel_launch(void* const* d_in, const int* in_sizes, int n_in,
                              void* d_out, int out_size, void* d_ws, size_t ws_size,
                              hipStream_t stream) {
    const float* x     = (const float*)d_in[0];
    const int*   ei    = (const int*)d_in[1];
    const float* Wl    = (const float*)d_in[2];
    const float* bl    = (const float*)d_in[3];
    const float* Wr    = (const float*)d_in[4];
    const float* br    = (const float*)d_in[5];
    const float* gamma = (const float*)d_in[8];
    const float* beta  = (const float*)d_in[9];
    const float* du    = (const float*)d_in[10];
    const float* att   = (const float*)d_in[6];
    const float* bias  = (const float*)d_in[7];

    const int N = in_sizes[0] / D;       // 10000
    const int E = in_sizes[1] / 2;       // 160000
    const int M = E + N;

    // workspace layout (int units)
    int* ws = (int*)d_ws;
    size_t off = 0;
    float* xl       = (float*)(ws + off); off += (size_t)N * D;
    float* xr       = (float*)(ws + off); off += (size_t)N * D;
    float* colsum   = (float*)(ws + off); off += D;
    float* colsumsq = (float*)(ws + off); off += D;
    int*   counts   = ws + off;           off += N;
    int*   rowstart = ws + off;           off += N + 1;
    int*   cursor   = ws + off;           off += N;
    int*   ssrc     = ws + off;           off += M;
    int*   eic      = ws + off;           off += 2 * E;
    int*   flag     = ws + off;           off += 1;
    off = (off + 3) & ~(size_t)3;                       // 16B align
    unsigned short* Bt = (unsigned short*)(ws + off);   off += 512 * 256 / 2;
    float* biascat  = (float*)(ws + off); off += 512;

    // zero: colsum, colsumsq, counts, rowstart, cursor (contiguous)
    size_t zero_bytes = (size_t)(2 * D + N + (N + 1) + N) * sizeof(int);
    hipMemsetAsync(colsum, 0, zero_bytes, stream);

    detect_kernel<<<1, 256, 0, stream>>>(ei, flag, 1024);
    convert_kernel<<<(2 * E + 255) / 256, 256, 0, stream>>>(ei, flag, eic, 2 * E);
    prep_kernel<<<512, 256, 0, stream>>>(Wl, bl, Wr, br, Bt, biascat);

    dim3 ggrid((N + 63) / 64, 8);
    mfma_gemm_kernel<<<ggrid, 256, 0, stream>>>(x, Bt, biascat, xl, xr, N);

    hist_kernel<<<(M + 255) / 256, 256, 0, stream>>>(eic, counts, E, N);
    scan_kernel<<<1, 1024, 0, stream>>>(counts, rowstart, N);
    scatter_kernel<<<(M + 255) / 256, 256, 0, stream>>>(eic, rowstart, cursor, ssrc, E, N);

    node_kernel<<<(N + 3) / 4, 256, 0, stream>>>(xl, xr, att, bias, du,
                                                 rowstart, ssrc, (float*)d_out, N);

    bn_reduce_kernel<<<256, 256, 0, stream>>>((const float*)d_out, colsum, colsumsq, N);
    bn_apply_kernel<<<(N * D / 4 + 255) / 256, 256, 0, stream>>>(
        (float*)d_out, colsum, colsumsq, gamma, beta, N);
}

// Round 3
// 208.504 us; speedup vs baseline: 1.2723x; 1.0122x over previous
//
#include <hip/hip_runtime.h>
#include <hip/hip_bf16.h>
#include <math.h>

// N=10000, E=160000, DIN=DOUT=256
#define D 256
#define NEG_SLOPE 0.2f
#define BN_EPS 1e-5f

typedef __attribute__((ext_vector_type(8))) short bf16x8;
typedef __attribute__((ext_vector_type(8))) unsigned short ushort8;
typedef __attribute__((ext_vector_type(4))) float f32x4;

__device__ inline unsigned short f2bf(float f) {
    union { float f; unsigned u; } v; v.f = f;
    unsigned u = v.u;
    unsigned r = u + 0x7FFFu + ((u >> 16) & 1u);   // RNE
    return (unsigned short)(r >> 16);
}
__device__ inline float bf2f(unsigned short u) {
    union { unsigned u; float f; } v; v.u = ((unsigned)u) << 16; return v.f;
}

// ---------------------------------------------------------------------------
// edge_index dtype detection (int64 little-endian => all odd words zero)
// ---------------------------------------------------------------------------
__global__ void detect_kernel(const int* __restrict__ ei, int* __restrict__ flag,
                              int nwords) {
    __shared__ int ok;
    if (threadIdx.x == 0) ok = 1;
    __syncthreads();
    for (int w = threadIdx.x * 2 + 1; w < nwords; w += 512) {
        if (ei[w] != 0) atomicAnd(&ok, 0);
    }
    __syncthreads();
    if (threadIdx.x == 0) *flag = ok;   // 1 => int64 layout
}

// ---------------------------------------------------------------------------
// prepare: [0,B1) convert edge idx + dst histogram; [B1,B1+512) Bt/bias prep;
//          [B1+512,...) X fp32 -> bf16
// ---------------------------------------------------------------------------
__global__ void prepare_kernel(const int* __restrict__ ei, const int* __restrict__ flag,
                               const float* __restrict__ Wl, const float* __restrict__ bl,
                               const float* __restrict__ Wr, const float* __restrict__ br,
                               const float* __restrict__ x,
                               int* __restrict__ eic, int* __restrict__ counts,
                               unsigned short* __restrict__ Bt, float* __restrict__ biascat,
                               unsigned short* __restrict__ Xbf, int E, int N) {
    int b = blockIdx.x;
    int nconv = (2 * E + 255) / 256;
    if (b < nconv) {
        int e = b * 256 + threadIdx.x;
        if (e < 2 * E) {
            int v = (*flag) ? ei[2 * e] : ei[e];
            eic[e] = v;
            if (e >= E) atomicAdd(&counts[v], 1);   // dst histogram
        }
    } else if (b < nconv + 512) {
        int n = b - nconv;
        int k = threadIdx.x;
        const float* W = (n < 256) ? Wl : Wr;
        int nn = n & 255;
        Bt[(size_t)n * 256 + k] = f2bf(W[(size_t)k * 256 + nn]);
        if (k == 0) biascat[n] = (n < 256) ? bl[nn] : br[nn];
    } else {
        size_t base = (size_t)(b - nconv - 512) * 2048 + (size_t)threadIdx.x * 8;
        if (base < (size_t)N * D) {
            float4 f0 = *(const float4*)(x + base);
            float4 f1 = *(const float4*)(x + base + 4);
            ushort8 v;
            v[0] = f2bf(f0.x); v[1] = f2bf(f0.y); v[2] = f2bf(f0.z); v[3] = f2bf(f0.w);
            v[4] = f2bf(f1.x); v[5] = f2bf(f1.y); v[6] = f2bf(f1.z); v[7] = f2bf(f1.w);
            *(ushort8*)(Xbf + base) = v;
        }
    }
}

// ---------------------------------------------------------------------------
// MFMA GEMM: [xl|xr][10000][256] = Xbf * [Wl|Wr]^T + biascat
// tile 64x64, BK=128; A,B staged bf16. xl stored bf16, xr fp32.
// ---------------------------------------------------------------------------
__global__ __launch_bounds__(256) void mfma_gemm_kernel(
    const unsigned short* __restrict__ Xbf, const unsigned short* __restrict__ Bt,
    const float* __restrict__ biascat,
    unsigned short* __restrict__ xlbf, float* __restrict__ xr, int M)
{
    __shared__ __align__(16) unsigned short As[64][136];
    __shared__ __align__(16) unsigned short Bs[64][136];

    const int tid = threadIdx.x;
    const int wave = tid >> 6, lane = tid & 63;
    const int m_l = lane & 15, quad = lane >> 4;
    const int row0 = blockIdx.x * 64;
    const int n0 = blockIdx.y * 64;

    f32x4 acc[4] = {};

    for (int k0 = 0; k0 < 256; k0 += 128) {
        __syncthreads();
        #pragma unroll
        for (int i = 0; i < 4; i++) {
            int c = tid + i * 256;          // 0..1023
            int r = c >> 4;                 // 0..63
            int u = (c & 15) * 8;           // 0..120
            int grow = row0 + r;
            ushort8 av = {0, 0, 0, 0, 0, 0, 0, 0};
            if (grow < M) av = *(const ushort8*)(Xbf + (size_t)grow * 256 + k0 + u);
            *(ushort8*)&As[r][u] = av;
            *(ushort8*)&Bs[r][u] = *(const ushort8*)(Bt + (size_t)(n0 + r) * 256 + k0 + u);
        }
        __syncthreads();

        #pragma unroll
        for (int kk0 = 0; kk0 < 128; kk0 += 32) {
            bf16x8 a = *(const bf16x8*)&As[wave * 16 + m_l][kk0 + quad * 8];
            #pragma unroll
            for (int c = 0; c < 4; c++) {
                bf16x8 b = *(const bf16x8*)&Bs[c * 16 + m_l][kk0 + quad * 8];
                acc[c] = __builtin_amdgcn_mfma_f32_16x16x32_bf16(a, b, acc[c], 0, 0, 0);
            }
        }
    }

    const bool isl = (n0 < 256);
    #pragma unroll
    for (int c = 0; c < 4; c++) {
        int col = n0 + c * 16 + m_l;
        float bv = biascat[col];
        int cc = col & 255;
        #pragma unroll
        for (int r = 0; r < 4; r++) {
            int row = row0 + wave * 16 + quad * 4 + r;
            if (row < M) {
                float v = acc[c][r] + bv;
                if (isl) xlbf[(size_t)row * 256 + cc] = f2bf(v);
                else     xr[(size_t)row * 256 + cc] = v;
            }
        }
    }
}

// ---------------------------------------------------------------------------
// scan: exclusive prefix over (counts[i] + 1)  (+1 folds in the self-loop)
// ---------------------------------------------------------------------------
__global__ __launch_bounds__(1024) void scan_kernel(const int* __restrict__ counts,
                                                    int* __restrict__ rowstart, int n) {
    __shared__ int wsum[16];
    __shared__ int carry_s;
    int tid = threadIdx.x, lane = tid & 63, wid = tid >> 6;
    if (tid == 0) carry_s = 0;
    __syncthreads();
    for (int base = 0; base < n; base += 1024) {
        int idx = base + tid;
        int v = (idx < n) ? counts[idx] + 1 : 0;
        int x = v;
        #pragma unroll
        for (int off = 1; off < 64; off <<= 1) {
            int y = __shfl_up(x, off);
            if (lane >= off) x += y;
        }
        if (lane == 63) wsum[wid] = x;
        __syncthreads();
        int total = 0;
        if (wid == 0) {
            int w = (lane < 16) ? wsum[lane] : 0;
            #pragma unroll
            for (int off = 1; off < 16; off <<= 1) {
                int y = __shfl_up(w, off);
                if (lane >= off) w += y;
            }
            if (lane < 16) wsum[lane] = w;
            total = w;
        }
        __syncthreads();
        int carry = carry_s;
        int woff = (wid > 0) ? wsum[wid - 1] : 0;
        if (idx < n) rowstart[idx] = carry + woff + x - v;
        __syncthreads();
        if (tid == 15) carry_s = carry + total;
        __syncthreads();
    }
    if (tid == 0) rowstart[n] = carry_s;
}

__global__ void scatter_kernel(const int* __restrict__ eic,
                               const int* __restrict__ rowstart,
                               int* __restrict__ cursor, int* __restrict__ ssrc,
                               int E, int N) {
    int e = blockIdx.x * 256 + threadIdx.x;
    int M = E + N;
    if (e >= M) return;
    int src, dst;
    if (e < E) { src = eic[e]; dst = eic[E + e]; }
    else       { src = dst = e - E; }
    int pos = rowstart[dst] + atomicAdd(&cursor[dst], 1);
    ssrc[pos] = src;
}

// ---------------------------------------------------------------------------
// One WAVE per node, 4 edges per iteration (4 interleaved shuffle chains),
// bf16 xl gather (8 B/lane/edge). bias+ReLU+dropout fused; writes pre-BN.
// ---------------------------------------------------------------------------
__device__ inline float dotleaky(float fx, float fy, float fz, float fw,
                                 float4 b4, float4 att4) {
    float hx = fx + b4.x; hx = (hx > 0.f) ? hx : NEG_SLOPE * hx;
    float hy = fy + b4.y; hy = (hy > 0.f) ? hy : NEG_SLOPE * hy;
    float hz = fz + b4.z; hz = (hz > 0.f) ? hz : NEG_SLOPE * hz;
    float hw = fw + b4.w; hw = (hw > 0.f) ? hw : NEG_SLOPE * hw;
    return hx * att4.x + hy * att4.y + hz * att4.z + hw * att4.w;
}

__global__ __launch_bounds__(256) void node_kernel(
    const unsigned short* __restrict__ xlbf, const float* __restrict__ xr,
    const float* __restrict__ att, const float* __restrict__ bias,
    const float* __restrict__ du, const int* __restrict__ rowstart,
    const int* __restrict__ ssrc, float* __restrict__ out, int N)
{
    const int wave = threadIdx.x >> 6, lane = threadIdx.x & 63;
    const int i = blockIdx.x * 4 + wave;
    if (i >= N) return;

    const float4 att4 = ((const float4*)att)[lane];
    const float4 b4 = ((const float4*)(xr + (size_t)i * D))[lane];
    const int start = rowstart[i], end = rowstart[i + 1];

    float m = -INFINITY, lsum = 0.f;
    float4 acc = make_float4(0.f, 0.f, 0.f, 0.f);
    const ushort4 z4 = make_ushort4(0, 0, 0, 0);

    int e = start;
    ushort4 p0, p1, p2, p3;
    p0 = *(const ushort4*)(xlbf + (size_t)ssrc[e] * D + lane * 4);   // deg >= 1
    p1 = (e + 1 < end) ? *(const ushort4*)(xlbf + (size_t)ssrc[e + 1] * D + lane * 4) : z4;
    p2 = (e + 2 < end) ? *(const ushort4*)(xlbf + (size_t)ssrc[e + 2] * D + lane * 4) : z4;
    p3 = (e + 3 < end) ? *(const ushort4*)(xlbf + (size_t)ssrc[e + 3] * D + lane * 4) : z4;

    while (true) {
        ushort4 c0 = p0, c1 = p1, c2 = p2, c3 = p3;
        int cnt = end - e; cnt = (cnt > 4) ? 4 : cnt;
        int en = e + 4;
        if (en < end) {
            p0 = *(const ushort4*)(xlbf + (size_t)ssrc[en] * D + lane * 4);
            p1 = (en + 1 < end) ? *(const ushort4*)(xlbf + (size_t)ssrc[en + 1] * D + lane * 4) : z4;
            p2 = (en + 2 < end) ? *(const ushort4*)(xlbf + (size_t)ssrc[en + 2] * D + lane * 4) : z4;
            p3 = (en + 3 < end) ? *(const ushort4*)(xlbf + (size_t)ssrc[en + 3] * D + lane * 4) : z4;
        }

        float f0x = bf2f(c0.x), f0y = bf2f(c0.y), f0z = bf2f(c0.z), f0w = bf2f(c0.w);
        float f1x = bf2f(c1.x), f1y = bf2f(c1.y), f1z = bf2f(c1.z), f1w = bf2f(c1.w);
        float f2x = bf2f(c2.x), f2y = bf2f(c2.y), f2z = bf2f(c2.z), f2w = bf2f(c2.w);
        float f3x = bf2f(c3.x), f3y = bf2f(c3.y), f3z = bf2f(c3.z), f3w = bf2f(c3.w);

        float s0 = dotleaky(f0x, f0y, f0z, f0w, b4, att4);
        float s1 = dotleaky(f1x, f1y, f1z, f1w, b4, att4);
        float s2 = dotleaky(f2x, f2y, f2z, f2w, b4, att4);
        float s3 = dotleaky(f3x, f3y, f3z, f3w, b4, att4);

        #pragma unroll
        for (int off = 1; off < 64; off <<= 1) {
            s0 += __shfl_xor(s0, off);
            s1 += __shfl_xor(s1, off);
            s2 += __shfl_xor(s2, off);
            s3 += __shfl_xor(s3, off);
        }
        if (cnt < 2) s1 = -INFINITY;
        if (cnt < 3) s2 = -INFINITY;
        if (cnt < 4) s3 = -INFINITY;

        float mnew = fmaxf(fmaxf(m, fmaxf(s0, s1)), fmaxf(s2, s3));
        float sc = __expf(m - mnew);           // 0 on first iteration
        float e0 = __expf(s0 - mnew);
        float e1 = __expf(s1 - mnew);          // 0 if masked
        float e2 = __expf(s2 - mnew);
        float e3 = __expf(s3 - mnew);
        lsum = lsum * sc + e0 + e1 + e2 + e3;
        acc.x = acc.x * sc + e0 * f0x + e1 * f1x + e2 * f2x + e3 * f3x;
        acc.y = acc.y * sc + e0 * f0y + e1 * f1y + e2 * f2y + e3 * f3y;
        acc.z = acc.z * sc + e0 * f0z + e1 * f1z + e2 * f2z + e3 * f3z;
        acc.w = acc.w * sc + e0 * f0w + e1 * f1w + e2 * f2w + e3 * f3w;
        m = mnew;
        e = en;
        if (e >= end) break;
    }

    float inv = 1.f / lsum;
    float4 bi = ((const float4*)bias)[lane];
    float4 u4 = ((const float4*)(du + (size_t)i * D))[lane];
    float4 o;
    o.x = fmaxf(acc.x * inv + bi.x, 0.f); o.x = (u4.x >= 0.5f) ? 2.f * o.x : 0.f;
    o.y = fmaxf(acc.y * inv + bi.y, 0.f); o.y = (u4.y >= 0.5f) ? 2.f * o.y : 0.f;
    o.z = fmaxf(acc.z * inv + bi.z, 0.f); o.z = (u4.z >= 0.5f) ? 2.f * o.z : 0.f;
    o.w = fmaxf(acc.w * inv + bi.w, 0.f); o.w = (u4.w >= 0.5f) ? 2.f * o.w : 0.f;
    ((float4*)(out + (size_t)i * D))[lane] = o;
}

// ---------------------------------------------------------------------------
// BatchNorm (training stats)
// ---------------------------------------------------------------------------
__global__ void bn_reduce_kernel(const float* __restrict__ pre,
                                 float* __restrict__ colsum,
                                 float* __restrict__ colsumsq, int N) {
    int t = threadIdx.x;
    float s = 0.f, s2 = 0.f;
    for (int r = blockIdx.x; r < N; r += gridDim.x) {
        float v = pre[(size_t)r * D + t];
        s += v; s2 += v * v;
    }
    atomicAdd(&colsum[t], s);
    atomicAdd(&colsumsq[t], s2);
}

__global__ void bn_apply_kernel(float* __restrict__ out,
                                const float* __restrict__ colsum,
                                const float* __restrict__ colsumsq,
                                const float* __restrict__ gamma,
                                const float* __restrict__ beta, int N) {
    int idx4 = blockIdx.x * 256 + threadIdx.x;
    int t0 = (idx4 * 4) & (D - 1);
    float invN = 1.f / (float)N;
    float4 v = ((const float4*)out)[idx4];
    float4 o;
    #pragma unroll
    for (int j = 0; j < 4; j++) {
        float mean = colsum[t0 + j] * invN;
        float var = colsumsq[t0 + j] * invN - mean * mean;
        float r = rsqrtf(var + BN_EPS);
        float vv = (j == 0) ? v.x : (j == 1) ? v.y : (j == 2) ? v.z : v.w;
        float oo = gamma[t0 + j] * (vv - mean) * r + beta[t0 + j];
        if (j == 0) o.x = oo; else if (j == 1) o.y = oo; else if (j == 2) o.z = oo; else o.w = oo;
    }
    ((float4*)out)[idx4] = o;
}

// ---------------------------------------------------------------------------
extern "C" void kernel_launch(void* const* d_in, const int* in_sizes, int n_in,
                              void* d_out, int out_size, void* d_ws, size_t ws_size,
                              hipStream_t stream) {
    const float* x     = (const float*)d_in[0];
    const int*   ei    = (const int*)d_in[1];
    const float* Wl    = (const float*)d_in[2];
    const float* bl    = (const float*)d_in[3];
    const float* Wr    = (const float*)d_in[4];
    const float* br    = (const float*)d_in[5];
    const float* att   = (const float*)d_in[6];
    const float* bias  = (const float*)d_in[7];
    const float* gamma = (const float*)d_in[8];
    const float* beta  = (const float*)d_in[9];
    const float* du    = (const float*)d_in[10];

    const int N = in_sizes[0] / D;       // 10000
    const int E = in_sizes[1] / 2;       // 160000
    const int M = E + N;

    // workspace layout (4-byte word units)
    int* ws = (int*)d_ws;
    size_t off = 0;
    float* xr       = (float*)(ws + off); off += (size_t)N * D;
    unsigned short* xlbf = (unsigned short*)(ws + off); off += (size_t)N * D / 2;
    unsigned short* Xbf  = (unsigned short*)(ws + off); off += (size_t)N * D / 2;
    unsigned short* Bt   = (unsigned short*)(ws + off); off += 512 * 256 / 2;
    float* biascat  = (float*)(ws + off); off += 512;
    int*   ssrc     = ws + off;           off += M;
    int*   eic      = ws + off;           off += 2 * E;
    int*   flag     = ws + off;           off += 1;
    off = (off + 3) & ~(size_t)3;
    // contiguous zeroed region:
    float* colsum   = (float*)(ws + off); off += D;
    float* colsumsq = (float*)(ws + off); off += D;
    int*   counts   = ws + off;           off += N;
    int*   rowstart = ws + off;           off += N + 1;
    int*   cursor   = ws + off;           off += N;

    size_t zero_bytes = (size_t)(2 * D + N + (N + 1) + N) * sizeof(int);
    hipMemsetAsync(colsum, 0, zero_bytes, stream);

    detect_kernel<<<1, 256, 0, stream>>>(ei, flag, 1024);

    int nconv = (2 * E + 255) / 256;
    int nxbf = (N * D + 2047) / 2048;
    prepare_kernel<<<nconv + 512 + nxbf, 256, 0, stream>>>(
        ei, flag, Wl, bl, Wr, br, x, eic, counts, Bt, biascat, Xbf, E, N);

    dim3 ggrid((N + 63) / 64, 8);
    mfma_gemm_kernel<<<ggrid, 256, 0, stream>>>(Xbf, Bt, biascat, xlbf, xr, N);

    scan_kernel<<<1, 1024, 0, stream>>>(counts, rowstart, N);
    scatter_kernel<<<(M + 255) / 256, 256, 0, stream>>>(eic, rowstart, cursor, ssrc, E, N);

    node_kernel<<<(N + 3) / 4, 256, 0, stream>>>(xlbf, xr, att, bias, du,
                                                 rowstart, ssrc, (float*)d_out, N);

    bn_reduce_kernel<<<256, 256, 0, stream>>>((const float*)d_out, colsum, colsumsq, N);
    bn_apply_kernel<<<(N * D / 4 + 255) / 256, 256, 0, stream>>>(
        (float*)d_out, colsum, colsumsq, gamma, beta, N);
}